// Round 8
// baseline (144.782 us; speedup 1.0000x reference)
//
#include <hip/hip_runtime.h>
#include <hip/hip_bf16.h>

// SConv: x(8,64,128,128) f32, Coefficient(9,9), W(128,64,3,3), b(128)
// out[b,co,h,w] = sum_{c,t} z[b,c,h,w][t] * W[co,c,t] + b[co]
// z = [sorted8(y[noncenter])[0:4], center, sorted8[4:8]],
// y_i = sum_j Coefficient[i,j] * patch_j (3x3 neighborhood, zero pad 1).
//
// Round 15 (post-mortem R14: occupancy 37->54% with ZERO dur change; pipe
// accounting shows VALU 24us + LDS 20us + HBM 20us + MFMA 8us ~= 72us ~=
// measured 67us -> the kernel runs its pipes SEQUENTIALLY, zero overlap.
// All prior rounds moved work between pipes; none made them concurrent):
//  - Software-pipelined tiles: block owns T=4 h-pair tiles (2h x 16w each),
//    Z double-buffered (2 x 37376 B). Between barriers, PhaseA(t+1) [VALU+
//    VMEM, all waves] runs concurrently with PhaseB(t) [MFMA+LDS, waves
//    0-3] -> MFMA/VALU wave co-schedule (m114) by construction.
//  - kh-split dropped: waves 0-3 full-K (36 MFMAs, nt=wave). No reduction,
//    no scratch, ONE barrier per tile (was 3).
//  - Row-carry: tile t+1 reuses 2 of its 4 x-rows from tile t's registers
//    -> 10 row-loads per thread per block (was 16) -> x FETCH ~-37%.
//  - Kept: k-permuted Z layout (1 ds_write_b128 + b16 tail/row), SROW 584
//    (73 granules %8=1 -> conflict-free b128 A-reads), 4-deep B prefetch
//    refilled at tile end (hides under barrier).
// LDS 74752 B -> 2 blocks/CU; launch_bounds(512,4) -> 128 VGPR cap.
// Layouts: A row=lane&31, k=(lane>>5)*8+e; C/D col=lane&31=co,
// row=(reg&3)+8*(reg>>2)+4*(lane>>5) (m74/m101).

#define B_   8
#define C_   64
#define H_   128
#define W_   128
#define CO_  128
#define K_   576    // C_*9 = 36*16
#define MT   32     // sites per tile (2h x 16w)
#define SROW 584    // LDS row stride in elements (1168 B = 73 granules)
#define TB   4      // tiles per block (h-pairs)

typedef __attribute__((ext_vector_type(8)))  short  short8;
typedef __attribute__((ext_vector_type(8)))  __bf16 bf16x8;
typedef __attribute__((ext_vector_type(16))) float  f32x16;
typedef __attribute__((ext_vector_type(2)))  float  f32x2;

__device__ __forceinline__ void cswap2(f32x2 &a, f32x2 &b) {
    f32x2 lo = __builtin_elementwise_min(a, b);
    f32x2 hi = __builtin_elementwise_max(a, b);
    a = lo; b = hi;
}

__device__ __forceinline__ ushort f2bf(float f) {
    union { float f; unsigned u; } v; v.f = f;
    unsigned r = v.u + 0x7fffu + ((v.u >> 16) & 1u);  // RNE
    return (ushort)(r >> 16);
}

__device__ __forceinline__ unsigned pack2bf(float lo, float hi) {
    union { __hip_bfloat162 h; unsigned u; } cv;
    cv.h = __float22bfloat162_rn(make_float2(lo, hi));  // x->low word
    return cv.u;
}

// Repack W[co][c*9+t] f32 -> Wb[((nt*36+ks)*64+lane)*8+e] bf16 where
// co = nt*32+(lane&31), k' = ks*16+(lane>>5)*8+e, and k' decodes as:
//   k' < 512:  rc = k'>>3, t = k'&7, c = ((rc&7)<<3)|(rc>>3)   (rho inverse)
//   k' >= 512: c = k'-512, t = 8
__global__ __launch_bounds__(256) void conv_W_bf16(const float* __restrict__ Wg,
                                                   ushort* __restrict__ Wb) {
    int i = blockIdx.x * 256 + threadIdx.x;
    if (i >= CO_ * K_) return;
    const int e    = i & 7;
    const int lane = (i >> 3) & 63;
    const int t9   = i >> 9;            // nt*36 + ks
    const int nt   = t9 / 36;
    const int ks   = t9 - nt * 36;
    const int co   = nt * 32 + (lane & 31);
    const int kp   = ks * 16 + (lane >> 5) * 8 + e;
    int c, t;
    if (kp < 512) { const int rc = kp >> 3; t = kp & 7; c = ((rc & 7) << 3) | (rc >> 3); }
    else          { c = kp - 512; t = 8; }
    Wb[i] = f2bf(Wg[co * K_ + c * 9 + t]);
}

// Load one padded x row (4 cols starting at w-1), absolute row hy.
__device__ __forceinline__ void load_row(const float* __restrict__ xb, int hy,
                                         int w, bool wint, float out[4]) {
    if (wint && (unsigned)hy < (unsigned)H_) {       // uniform fast path
        float4 v; __builtin_memcpy(&v, xb + hy * W_ + (w - 1), 16);
        out[0] = v.x; out[1] = v.y; out[2] = v.z; out[3] = v.w;
    } else {                                         // clamped + selects
        const bool hok = (unsigned)hy < (unsigned)H_;
        const int hc = min(max(hy, 0), H_ - 1);
        const int wm = w - 1;
        const int wc = min(max(wm, 0), W_ - 4);
        const int s  = wm - wc;                      // -1, 0, +1
        float4 v; __builtin_memcpy(&v, xb + hc * W_ + wc, 16);
        const float r0 = (s < 0) ? 0.f : ((s > 0) ? v.y : v.x);
        const float r1 = (s < 0) ? v.x : ((s > 0) ? v.z : v.y);
        const float r2 = (s < 0) ? v.y : ((s > 0) ? v.w : v.z);
        const float r3 = (s < 0) ? v.z : ((s > 0) ? 0.f : v.w);
        out[0] = hok ? r0 : 0.f; out[1] = hok ? r1 : 0.f;
        out[2] = hok ? r2 : 0.f; out[3] = hok ? r3 : 0.f;
    }
}

// Compute z for 2w x 2h sites from 4 rows; store into buffer (k-permuted).
__device__ __forceinline__ void zstore_tile(const float (&rr)[4][4],
                                            const float* __restrict__ Coef,
                                            char* bufb, int rcb, int tailb, int pw) {
    #pragma unroll
    for (int hl = 0; hl < 2; ++hl) {
        f32x2 p2[9];
        #pragma unroll
        for (int dy = 0; dy < 3; ++dy)
            #pragma unroll
            for (int dx = 0; dx < 3; ++dx)
                p2[dy * 3 + dx] = (f32x2){ rr[hl + dy][dx], rr[hl + dy][dx + 1] };

        f32x2 v2[8];
        #pragma unroll
        for (int ii = 0; ii < 8; ++ii) {
            const int i = ii + (ii >> 2);
            f32x2 acc = p2[0] * Coef[i * 9];
            #pragma unroll
            for (int jj = 1; jj < 9; ++jj) acc += p2[jj] * Coef[i * 9 + jj];
            v2[ii] = acc;
        }

        // Batcher odd-even mergesort, 8 elems, ascending (19 comparators)
        cswap2(v2[0],v2[1]); cswap2(v2[2],v2[3]); cswap2(v2[4],v2[5]); cswap2(v2[6],v2[7]);
        cswap2(v2[0],v2[2]); cswap2(v2[1],v2[3]); cswap2(v2[4],v2[6]); cswap2(v2[5],v2[7]);
        cswap2(v2[1],v2[2]); cswap2(v2[5],v2[6]);
        cswap2(v2[0],v2[4]); cswap2(v2[1],v2[5]); cswap2(v2[2],v2[6]); cswap2(v2[3],v2[7]);
        cswap2(v2[2],v2[4]); cswap2(v2[3],v2[5]);
        cswap2(v2[1],v2[2]); cswap2(v2[3],v2[4]); cswap2(v2[5],v2[6]);

        // z order: s0 s1 s2 s3 center s4 s5 s6 | s7 -> tail (t=8 slot)
        f32x2 z2[9] = { v2[0], v2[1], v2[2], v2[3], p2[4],
                        v2[4], v2[5], v2[6], v2[7] };

        char* zb0 = bufb + (size_t)(hl * 16 + pw * 2) * (SROW * 2);
        char* zb1 = zb0 + SROW * 2;
        uint4 q0 = make_uint4(pack2bf(z2[0][0], z2[1][0]), pack2bf(z2[2][0], z2[3][0]),
                              pack2bf(z2[4][0], z2[5][0]), pack2bf(z2[6][0], z2[7][0]));
        uint4 q1 = make_uint4(pack2bf(z2[0][1], z2[1][1]), pack2bf(z2[2][1], z2[3][1]),
                              pack2bf(z2[4][1], z2[5][1]), pack2bf(z2[6][1], z2[7][1]));
        *(uint4*)(zb0 + rcb) = q0;                 // one b128, conflict-free
        *(uint4*)(zb1 + rcb) = q1;
        *(ushort*)(zb0 + tailb) = f2bf(z2[8][0]);  // t=8 tail
        *(ushort*)(zb1 + tailb) = f2bf(z2[8][1]);
    }
}

__global__ __launch_bounds__(512, 4) void sconv_mfma(
    const float* __restrict__ x,
    const float* __restrict__ Coef,
    const ushort* __restrict__ Wb,     // bf16 bits, repacked (see above)
    const float* __restrict__ bias,
    float* __restrict__ out)
{
    __shared__ __align__(16) ushort Zl[2][MT * SROW];   // 74752 B -> 2 blocks/CU

    const int tid = threadIdx.x;
    const int bx  = blockIdx.x;
    const int wq  = bx & 7;            // 16-wide w slice
    const int hq  = (bx >> 3) & 15;    // 8-row h band
    const int b   = bx >> 7;
    const int w0  = wq * 16;
    const int h0b = hq * 8;

    const int wave = tid >> 6;
    const int lane = tid & 63;
    const int nt   = wave & 3;         // n-tile for waves 0-3
    const int r31  = lane & 31;
    const int u    = lane >> 5;
    const ushort* bptr = Wb + ((size_t)(nt * 36) * 64 + lane) * 8;

    // Phase-A mapping (per thread: 1 channel, 2w x 2h sites)
    const int j  = (tid >> 3) & 7;
    const int c  = wave + 8 * j;               // rho(c) = 8*wave + j
    const int pw = tid & 7;
    const int w  = w0 + pw * 2;
    const float* xb = x + ((size_t)(b * C_ + c)) * (H_ * W_);
    const bool wint = (w0 >= 16) && (w0 <= 96);
    const int rcb   = (wave * 8 + j) << 4;     // rho(c)*16 byte granule
    const int tailb = 1024 + 2 * c;            // t=8 element byte offset

    // B prefetch (hides L2 latency under prologue PhaseA + barrier)
    short8 bq[4];
    if (wave < 4) {
        #pragma unroll
        for (int i = 0; i < 4; ++i) bq[i] = *(const short8*)(bptr + i * 512);
    }

    // ---- Prologue: PhaseA(tile 0) -> buf0 ----
    float rr[4][4];                            // rolling padded rows
    load_row(xb, h0b - 1, w, wint, rr[0]);
    load_row(xb, h0b + 0, w, wint, rr[1]);
    load_row(xb, h0b + 1, w, wint, rr[2]);
    load_row(xb, h0b + 2, w, wint, rr[3]);
    zstore_tile(rr, Coef, (char*)&Zl[0][0], rcb, tailb, pw);
    __syncthreads();

    // ---- Pipelined main loop: PhaseA(t+1) overlaps PhaseB(t) ----
    for (int t = 0; t < TB; ++t) {
        if (t < TB - 1) {                      // PhaseA for next tile
            #pragma unroll
            for (int q2 = 0; q2 < 4; ++q2) { rr[0][q2] = rr[2][q2]; rr[1][q2] = rr[3][q2]; }
            const int h0n = h0b + 2 * (t + 1);
            load_row(xb, h0n + 1, w, wint, rr[2]);
            load_row(xb, h0n + 2, w, wint, rr[3]);
            zstore_tile(rr, Coef, (char*)&Zl[(t + 1) & 1][0], rcb, tailb, pw);
        }
        if (wave < 4) {                        // PhaseB for current tile
            const char* abase = (const char*)&Zl[t & 1][0] + (size_t)r31 * (SROW * 2) + u * 16;
            bf16x8 aq[2];
            aq[0] = *(const bf16x8*)(abase + 0);
            aq[1] = *(const bf16x8*)(abase + 32);
            f32x16 acc = {};
            #pragma unroll
            for (int ks = 0; ks < 36; ++ks) {
                bf16x8 a  = aq[ks & 1];
                short8 bb = bq[ks & 3];
                if (ks + 2 < 36)
                    aq[ks & 1] = *(const bf16x8*)(abase + (ks + 2) * 32);
                if (ks + 4 < 36)
                    bq[ks & 3] = *(const short8*)(bptr + (ks + 4) * 512);
                acc = __builtin_amdgcn_mfma_f32_32x32x16_bf16(a, __builtin_bit_cast(bf16x8, bb), acc, 0, 0, 0);
            }
            if (t < TB - 1) {                  // refill B queue for next tile
                #pragma unroll
                for (int i = 0; i < 4; ++i) bq[i] = *(const short8*)(bptr + i * 512);
            }
            // Epilogue: D col=lane&31=co-local; row=(reg&3)+8*(reg>>2)+4u=m
            const int h0t = h0b + 2 * t;
            const int co  = nt * 32 + r31;
            const float bv = bias[co];
            float* obase = out + (((size_t)(b * CO_ + co)) * H_ + h0t) * W_ + w0;
            #pragma unroll
            for (int qq = 0; qq < 4; ++qq) {
                const int roff = qq * 8 + u * 4;
                const int hl   = roff >> 4;    // 0/1 -> h0t / h0t+1
                const int wl   = roff & 15;    // 0,4,8,12
                *(float4*)(obase + hl * W_ + wl) =
                    make_float4(acc[qq*4+0] + bv, acc[qq*4+1] + bv,
                                acc[qq*4+2] + bv, acc[qq*4+3] + bv);
            }
        }
        __syncthreads();
    }
}

// ---- fp32 fallback (round-1 kernel, direct W layout) if ws is too small ----
#define WT 16
__device__ __forceinline__ void cswap(float &a, float &b) {
    float lo = fminf(a, b);
    float hi = fmaxf(a, b);
    a = lo; b = hi;
}
__global__ __launch_bounds__(256) void sconv_fp32(
    const float* __restrict__ x, const float* __restrict__ Coef,
    const float* __restrict__ Wg, const float* __restrict__ bias,
    float* __restrict__ out)
{
    __shared__ float Cf[81];
    __shared__ float Zl[C_ * 9 * WT];
    const int tid = threadIdx.x;
    const int bx  = blockIdx.x;
    const int wt  = bx & 7;
    const int h   = (bx >> 3) & 127;
    const int b   = bx >> 10;
    const int w0  = wt * WT;
    if (tid < 81) Cf[tid] = Coef[tid];
    __syncthreads();
    for (int task = tid; task < C_ * WT; task += 256) {
        const int c = task >> 4, wl = task & 15, w = w0 + wl;
        const float* xb = x + (b * C_ + c) * H_ * W_;
        float p[9];
        #pragma unroll
        for (int dy = 0; dy < 3; ++dy) {
            const int hy = h + dy - 1; const bool hin = (unsigned)hy < (unsigned)H_;
            #pragma unroll
            for (int dx = 0; dx < 3; ++dx) {
                const int wx = w + dx - 1; const bool win = (unsigned)wx < (unsigned)W_;
                p[dy * 3 + dx] = (hin && win) ? xb[hy * W_ + wx] : 0.0f;
            }
        }
        float v[8];
        #pragma unroll
        for (int ii = 0; ii < 8; ++ii) {
            const int i = ii + (ii >> 2);
            float acc = 0.0f;
            #pragma unroll
            for (int jj = 0; jj < 9; ++jj) acc = fmaf(Cf[i * 9 + jj], p[jj], acc);
            v[ii] = acc;
        }
        cswap(v[0], v[1]); cswap(v[2], v[3]); cswap(v[4], v[5]); cswap(v[6], v[7]);
        cswap(v[0], v[2]); cswap(v[1], v[3]); cswap(v[4], v[6]); cswap(v[5], v[7]);
        cswap(v[1], v[2]); cswap(v[5], v[6]);
        cswap(v[0], v[4]); cswap(v[1], v[5]); cswap(v[2], v[6]); cswap(v[3], v[7]);
        cswap(v[2], v[4]); cswap(v[3], v[5]);
        cswap(v[1], v[2]); cswap(v[3], v[4]); cswap(v[5], v[6]);
        const int base = c * 9 * WT + wl;
        Zl[base + 0*WT]=v[0]; Zl[base + 1*WT]=v[1]; Zl[base + 2*WT]=v[2]; Zl[base + 3*WT]=v[3];
        Zl[base + 4*WT]=p[4];
        Zl[base + 5*WT]=v[4]; Zl[base + 6*WT]=v[5]; Zl[base + 7*WT]=v[6]; Zl[base + 8*WT]=v[7];
    }
    __syncthreads();
    const int co = tid >> 1, w0l = (tid & 1) * 8;
    float acc[8];
    #pragma unroll
    for (int i = 0; i < 8; ++i) acc[i] = 0.0f;
    for (int c = 0; c < C_; ++c) {
        #pragma unroll
        for (int t = 0; t < 9; ++t) {
            const float wv = Wg[(co * C_ + c) * 9 + t];
            const float* zp = &Zl[(c * 9 + t) * WT + w0l];
            const float4 za = *(const float4*)zp;
            const float4 zb = *(const float4*)(zp + 4);
            acc[0]=fmaf(za.x,wv,acc[0]); acc[1]=fmaf(za.y,wv,acc[1]);
            acc[2]=fmaf(za.z,wv,acc[2]); acc[3]=fmaf(za.w,wv,acc[3]);
            acc[4]=fmaf(zb.x,wv,acc[4]); acc[5]=fmaf(zb.y,wv,acc[5]);
            acc[6]=fmaf(zb.z,wv,acc[6]); acc[7]=fmaf(zb.w,wv,acc[7]);
        }
    }
    const float bv = bias[co];
    float* op = out + ((b * CO_ + co) * H_ + h) * W_ + w0 + w0l;
    *(float4*)(op)     = make_float4(acc[0]+bv, acc[1]+bv, acc[2]+bv, acc[3]+bv);
    *(float4*)(op + 4) = make_float4(acc[4]+bv, acc[5]+bv, acc[6]+bv, acc[7]+bv);
}

extern "C" void kernel_launch(void* const* d_in, const int* in_sizes, int n_in,
                              void* d_out, int out_size, void* d_ws, size_t ws_size,
                              hipStream_t stream) {
    const float* x    = (const float*)d_in[0];
    const float* Coef = (const float*)d_in[1];
    const float* Wg   = (const float*)d_in[2];
    const float* bias = (const float*)d_in[3];
    float* out = (float*)d_out;

    const size_t need = (size_t)CO_ * K_ * sizeof(ushort);   // 147456 B
    if (ws_size >= need) {
        ushort* Wb = (ushort*)d_ws;
        conv_W_bf16<<<(CO_ * K_ + 255) / 256, 256, 0, stream>>>(Wg, Wb);
        sconv_mfma<<<B_ * (H_ / 8) * (W_ / 16), 512, 0, stream>>>(x, Coef, Wb, bias, out);
    } else {
        sconv_fp32<<<B_ * H_ * 8, 256, 0, stream>>>(x, Coef, Wg, bias, out);
    }
}

// Round 9
// 139.814 us; speedup vs baseline: 1.0355x; 1.0355x over previous
//
#include <hip/hip_runtime.h>
#include <hip/hip_bf16.h>

// SConv: x(8,64,128,128) f32, Coefficient(9,9), W(128,64,3,3), b(128)
// out[b,co,h,w] = sum_{c,t} z[b,c,h,w][t] * W[co,c,t] + b[co]
// z = [sorted8(y[noncenter])[0:4], center, sorted8[4:8]],
// y_i = sum_j Coefficient[i,j] * patch_j (3x3 neighborhood, zero pad 1).
//
// Round 16 (post-mortem R15: tile-pipelining failed because PhaseA(t+1) and
// PhaseB(t) were in the SAME threads' instruction stream — waves 0-3 ran
// them serially, so the critical path never shrank. MfmaUtil/VALU flat.)
//  - TRUE producer/consumer wave specialization: waves 4-7 ONLY PhaseA
//    (2 channels/thread), waves 0-3 ONLY PhaseB (nt=wave, full K). Between
//    barriers a SIMD hosts pure-VALU waves and pure-MFMA/LDS waves
//    concurrently (m114 co-schedule, structurally forced).
//  - TB=8 tiles (16-row band), grid 512 = 2 blocks/CU; dbuf Z 74752 B;
//    ONE barrier per tile.
//  - Producer c-map c1=8j+wp, c2=c1+4 keeps rho(c) quad=j -> conflict-free
//    b128 stores (8 lanes/16B-slot). Consumer reads conflict-free (SROW
//    584: 73 granules %8=1).
//  - Consumer queues: A 4-deep (ds ~120cy), B 6-deep (L2 ~250cy), refilled
//    at tile end (same fragments each tile, L1/L2-hot).
// Layouts: A row=lane&31, k=(lane>>5)*8+e; C/D col=lane&31=co,
// row=(reg&3)+8*(reg>>2)+4*(lane>>5) (m74/m101).

#define B_   8
#define C_   64
#define H_   128
#define W_   128
#define CO_  128
#define K_   576    // C_*9 = 36*16
#define MT   32     // sites per tile (2h x 16w)
#define SROW 584    // LDS row stride in elements (1168 B = 73 granules)
#define TB   8      // tiles per block (h-pairs; 16-row band)

typedef __attribute__((ext_vector_type(8)))  short  short8;
typedef __attribute__((ext_vector_type(8)))  __bf16 bf16x8;
typedef __attribute__((ext_vector_type(16))) float  f32x16;
typedef __attribute__((ext_vector_type(2)))  float  f32x2;

__device__ __forceinline__ void cswap2(f32x2 &a, f32x2 &b) {
    f32x2 lo = __builtin_elementwise_min(a, b);
    f32x2 hi = __builtin_elementwise_max(a, b);
    a = lo; b = hi;
}

__device__ __forceinline__ ushort f2bf(float f) {
    union { float f; unsigned u; } v; v.f = f;
    unsigned r = v.u + 0x7fffu + ((v.u >> 16) & 1u);  // RNE
    return (ushort)(r >> 16);
}

__device__ __forceinline__ unsigned pack2bf(float lo, float hi) {
    union { __hip_bfloat162 h; unsigned u; } cv;
    cv.h = __float22bfloat162_rn(make_float2(lo, hi));  // x->low word
    return cv.u;
}

// Repack W[co][c*9+t] f32 -> Wb[((nt*36+ks)*64+lane)*8+e] bf16 where
// co = nt*32+(lane&31), k' = ks*16+(lane>>5)*8+e, and k' decodes as:
//   k' < 512:  rc = k'>>3, t = k'&7, c = ((rc&7)<<3)|(rc>>3)   (rho inverse)
//   k' >= 512: c = k'-512, t = 8
__global__ __launch_bounds__(256) void conv_W_bf16(const float* __restrict__ Wg,
                                                   ushort* __restrict__ Wb) {
    int i = blockIdx.x * 256 + threadIdx.x;
    if (i >= CO_ * K_) return;
    const int e    = i & 7;
    const int lane = (i >> 3) & 63;
    const int t9   = i >> 9;            // nt*36 + ks
    const int nt   = t9 / 36;
    const int ks   = t9 - nt * 36;
    const int co   = nt * 32 + (lane & 31);
    const int kp   = ks * 16 + (lane >> 5) * 8 + e;
    int c, t;
    if (kp < 512) { const int rc = kp >> 3; t = kp & 7; c = ((rc & 7) << 3) | (rc >> 3); }
    else          { c = kp - 512; t = 8; }
    Wb[i] = f2bf(Wg[co * K_ + c * 9 + t]);
}

// Load one padded x row (4 cols starting at w-1), absolute row hy.
__device__ __forceinline__ void load_row(const float* __restrict__ xb, int hy,
                                         int w, bool wint, float out[4]) {
    if (wint && (unsigned)hy < (unsigned)H_) {       // uniform fast path
        float4 v; __builtin_memcpy(&v, xb + hy * W_ + (w - 1), 16);
        out[0] = v.x; out[1] = v.y; out[2] = v.z; out[3] = v.w;
    } else {                                         // clamped + selects
        const bool hok = (unsigned)hy < (unsigned)H_;
        const int hc = min(max(hy, 0), H_ - 1);
        const int wm = w - 1;
        const int wc = min(max(wm, 0), W_ - 4);
        const int s  = wm - wc;                      // -1, 0, +1
        float4 v; __builtin_memcpy(&v, xb + hc * W_ + wc, 16);
        const float r0 = (s < 0) ? 0.f : ((s > 0) ? v.y : v.x);
        const float r1 = (s < 0) ? v.x : ((s > 0) ? v.z : v.y);
        const float r2 = (s < 0) ? v.y : ((s > 0) ? v.w : v.z);
        const float r3 = (s < 0) ? v.z : ((s > 0) ? 0.f : v.w);
        out[0] = hok ? r0 : 0.f; out[1] = hok ? r1 : 0.f;
        out[2] = hok ? r2 : 0.f; out[3] = hok ? r3 : 0.f;
    }
}

// Compute z for 2w x 2h sites from 4 rows; store into buffer (k-permuted).
__device__ __forceinline__ void zstore_tile(const float (&rr)[4][4],
                                            const float* __restrict__ Coef,
                                            char* bufb, int rcb, int tailb, int pw) {
    #pragma unroll
    for (int hl = 0; hl < 2; ++hl) {
        f32x2 p2[9];
        #pragma unroll
        for (int dy = 0; dy < 3; ++dy)
            #pragma unroll
            for (int dx = 0; dx < 3; ++dx)
                p2[dy * 3 + dx] = (f32x2){ rr[hl + dy][dx], rr[hl + dy][dx + 1] };

        f32x2 v2[8];
        #pragma unroll
        for (int ii = 0; ii < 8; ++ii) {
            const int i = ii + (ii >> 2);
            f32x2 acc = p2[0] * Coef[i * 9];
            #pragma unroll
            for (int jj = 1; jj < 9; ++jj) acc += p2[jj] * Coef[i * 9 + jj];
            v2[ii] = acc;
        }

        // Batcher odd-even mergesort, 8 elems, ascending (19 comparators)
        cswap2(v2[0],v2[1]); cswap2(v2[2],v2[3]); cswap2(v2[4],v2[5]); cswap2(v2[6],v2[7]);
        cswap2(v2[0],v2[2]); cswap2(v2[1],v2[3]); cswap2(v2[4],v2[6]); cswap2(v2[5],v2[7]);
        cswap2(v2[1],v2[2]); cswap2(v2[5],v2[6]);
        cswap2(v2[0],v2[4]); cswap2(v2[1],v2[5]); cswap2(v2[2],v2[6]); cswap2(v2[3],v2[7]);
        cswap2(v2[2],v2[4]); cswap2(v2[3],v2[5]);
        cswap2(v2[1],v2[2]); cswap2(v2[3],v2[4]); cswap2(v2[5],v2[6]);

        // z order: s0 s1 s2 s3 center s4 s5 s6 | s7 -> tail (t=8 slot)
        f32x2 z2[9] = { v2[0], v2[1], v2[2], v2[3], p2[4],
                        v2[4], v2[5], v2[6], v2[7] };

        char* zb0 = bufb + (size_t)(hl * 16 + pw * 2) * (SROW * 2);
        char* zb1 = zb0 + SROW * 2;
        uint4 q0 = make_uint4(pack2bf(z2[0][0], z2[1][0]), pack2bf(z2[2][0], z2[3][0]),
                              pack2bf(z2[4][0], z2[5][0]), pack2bf(z2[6][0], z2[7][0]));
        uint4 q1 = make_uint4(pack2bf(z2[0][1], z2[1][1]), pack2bf(z2[2][1], z2[3][1]),
                              pack2bf(z2[4][1], z2[5][1]), pack2bf(z2[6][1], z2[7][1]));
        *(uint4*)(zb0 + rcb) = q0;                 // one b128, conflict-free
        *(uint4*)(zb1 + rcb) = q1;
        *(ushort*)(zb0 + tailb) = f2bf(z2[8][0]);  // t=8 tail
        *(ushort*)(zb1 + tailb) = f2bf(z2[8][1]);
    }
}

__global__ __launch_bounds__(512, 4) void sconv_mfma(
    const float* __restrict__ x,
    const float* __restrict__ Coef,
    const ushort* __restrict__ Wb,     // bf16 bits, repacked (see above)
    const float* __restrict__ bias,
    float* __restrict__ out)
{
    __shared__ __align__(16) ushort Zl[2][MT * SROW];   // 74752 B -> 2 blocks/CU

    const int tid = threadIdx.x;
    const int bx  = blockIdx.x;
    const int wq  = bx & 7;            // 16-wide w slice
    const int hq  = (bx >> 3) & 7;     // 16-row h band
    const int b   = bx >> 6;
    const int w0  = wq * 16;
    const int h0b = hq * 16;

    const int wave = tid >> 6;
    const int lane = tid & 63;
    const int r31  = lane & 31;
    const int u    = lane >> 5;

    if (wave < 4) {
        // ================= CONSUMER: PhaseB only (nt = wave) =================
        const int nt = wave;
        const ushort* bptr = Wb + ((size_t)(nt * 36) * 64 + lane) * 8;
        const int co  = nt * 32 + r31;
        const float bv = bias[co];

        short8 bq[6];
        #pragma unroll
        for (int i = 0; i < 6; ++i) bq[i] = *(const short8*)(bptr + i * 512);

        __syncthreads();                       // wait for PhaseA(tile 0)

        for (int t = 0; t < TB; ++t) {
            const char* abase = (const char*)&Zl[t & 1][0]
                                + (size_t)r31 * (SROW * 2) + u * 16;
            bf16x8 aq[4];
            #pragma unroll
            for (int i = 0; i < 4; ++i)
                aq[i] = *(const bf16x8*)(abase + i * 32);

            f32x16 acc = {};
            #pragma unroll
            for (int ks = 0; ks < 36; ++ks) {
                bf16x8 a  = aq[ks & 3];
                short8 bb = bq[ks % 6];
                if (ks + 4 < 36)
                    aq[ks & 3] = *(const bf16x8*)(abase + (ks + 4) * 32);
                if (ks + 6 < 36)
                    bq[ks % 6] = *(const short8*)(bptr + (ks + 6) * 512);
                acc = __builtin_amdgcn_mfma_f32_32x32x16_bf16(
                          a, __builtin_bit_cast(bf16x8, bb), acc, 0, 0, 0);
            }
            if (t < TB - 1) {                  // refill for next tile (hot)
                #pragma unroll
                for (int i = 0; i < 6; ++i) bq[i] = *(const short8*)(bptr + i * 512);
            }
            // Epilogue: D col=lane&31=co-local; row=(reg&3)+8*(reg>>2)+4u=m
            const int h0t = h0b + 2 * t;
            float* obase = out + (((size_t)(b * CO_ + co)) * H_ + h0t) * W_ + w0;
            #pragma unroll
            for (int qq = 0; qq < 4; ++qq) {
                const int roff = qq * 8 + u * 4;
                const int hl   = roff >> 4;    // 0/1 -> h0t / h0t+1
                const int wl   = roff & 15;    // 0,4,8,12
                *(float4*)(obase + hl * W_ + wl) =
                    make_float4(acc[qq*4+0] + bv, acc[qq*4+1] + bv,
                                acc[qq*4+2] + bv, acc[qq*4+3] + bv);
            }
            __syncthreads();
        }
    } else {
        // ================= PRODUCER: PhaseA only (2 channels) ================
        const int wp = wave - 4;               // 0..3
        const int j  = lane >> 3;              // 0..7
        const int pw = lane & 7;               // 0..7
        const int c1 = 8 * j + wp;             // rho(c1) = 8*wp + j
        const int c2 = c1 + 4;                 // rho(c2) = 8*(wp+4) + j
        const int w  = w0 + pw * 2;
        const float* xb1 = x + ((size_t)(b * C_ + c1)) * (H_ * W_);
        const float* xb2 = x + ((size_t)(b * C_ + c2)) * (H_ * W_);
        const bool wint = (w0 >= 16) && (w0 <= 96);
        const int rcb1   = (8 * wp + j) << 4;  // granule byte offset
        const int rcb2   = rcb1 + 512;
        const int tailb1 = 1024 + 2 * c1;
        const int tailb2 = 1024 + 2 * c2;

        float r1[4][4], r2[4][4];
        load_row(xb1, h0b - 1, w, wint, r1[0]); load_row(xb2, h0b - 1, w, wint, r2[0]);
        load_row(xb1, h0b + 0, w, wint, r1[1]); load_row(xb2, h0b + 0, w, wint, r2[1]);
        load_row(xb1, h0b + 1, w, wint, r1[2]); load_row(xb2, h0b + 1, w, wint, r2[2]);
        load_row(xb1, h0b + 2, w, wint, r1[3]); load_row(xb2, h0b + 2, w, wint, r2[3]);
        zstore_tile(r1, Coef, (char*)&Zl[0][0], rcb1, tailb1, pw);
        zstore_tile(r2, Coef, (char*)&Zl[0][0], rcb2, tailb2, pw);
        __syncthreads();                       // publish tile 0

        for (int t = 0; t < TB; ++t) {
            if (t < TB - 1) {                  // build tile t+1 into other buf
                #pragma unroll
                for (int q2 = 0; q2 < 4; ++q2) {
                    r1[0][q2] = r1[2][q2]; r1[1][q2] = r1[3][q2];
                    r2[0][q2] = r2[2][q2]; r2[1][q2] = r2[3][q2];
                }
                const int h0n = h0b + 2 * (t + 1);
                load_row(xb1, h0n + 1, w, wint, r1[2]); load_row(xb2, h0n + 1, w, wint, r2[2]);
                load_row(xb1, h0n + 2, w, wint, r1[3]); load_row(xb2, h0n + 2, w, wint, r2[3]);
                char* bufb = (char*)&Zl[(t + 1) & 1][0];
                zstore_tile(r1, Coef, bufb, rcb1, tailb1, pw);
                zstore_tile(r2, Coef, bufb, rcb2, tailb2, pw);
            }
            __syncthreads();
        }
    }
}

// ---- fp32 fallback (round-1 kernel, direct W layout) if ws is too small ----
#define WT 16
__device__ __forceinline__ void cswap(float &a, float &b) {
    float lo = fminf(a, b);
    float hi = fmaxf(a, b);
    a = lo; b = hi;
}
__global__ __launch_bounds__(256) void sconv_fp32(
    const float* __restrict__ x, const float* __restrict__ Coef,
    const float* __restrict__ Wg, const float* __restrict__ bias,
    float* __restrict__ out)
{
    __shared__ float Cf[81];
    __shared__ float Zl[C_ * 9 * WT];
    const int tid = threadIdx.x;
    const int bx  = blockIdx.x;
    const int wt  = bx & 7;
    const int h   = (bx >> 3) & 127;
    const int b   = bx >> 10;
    const int w0  = wt * WT;
    if (tid < 81) Cf[tid] = Coef[tid];
    __syncthreads();
    for (int task = tid; task < C_ * WT; task += 256) {
        const int c = task >> 4, wl = task & 15, w = w0 + wl;
        const float* xb = x + (b * C_ + c) * H_ * W_;
        float p[9];
        #pragma unroll
        for (int dy = 0; dy < 3; ++dy) {
            const int hy = h + dy - 1; const bool hin = (unsigned)hy < (unsigned)H_;
            #pragma unroll
            for (int dx = 0; dx < 3; ++dx) {
                const int wx = w + dx - 1; const bool win = (unsigned)wx < (unsigned)W_;
                p[dy * 3 + dx] = (hin && win) ? xb[hy * W_ + wx] : 0.0f;
            }
        }
        float v[8];
        #pragma unroll
        for (int ii = 0; ii < 8; ++ii) {
            const int i = ii + (ii >> 2);
            float acc = 0.0f;
            #pragma unroll
            for (int jj = 0; jj < 9; ++jj) acc = fmaf(Cf[i * 9 + jj], p[jj], acc);
            v[ii] = acc;
        }
        cswap(v[0], v[1]); cswap(v[2], v[3]); cswap(v[4], v[5]); cswap(v[6], v[7]);
        cswap(v[0], v[2]); cswap(v[1], v[3]); cswap(v[4], v[6]); cswap(v[5], v[7]);
        cswap(v[1], v[2]); cswap(v[5], v[6]);
        cswap(v[0], v[4]); cswap(v[1], v[5]); cswap(v[2], v[6]); cswap(v[3], v[7]);
        cswap(v[2], v[4]); cswap(v[3], v[5]);
        cswap(v[1], v[2]); cswap(v[3], v[4]); cswap(v[5], v[6]);
        const int base = c * 9 * WT + wl;
        Zl[base + 0*WT]=v[0]; Zl[base + 1*WT]=v[1]; Zl[base + 2*WT]=v[2]; Zl[base + 3*WT]=v[3];
        Zl[base + 4*WT]=p[4];
        Zl[base + 5*WT]=v[4]; Zl[base + 6*WT]=v[5]; Zl[base + 7*WT]=v[6]; Zl[base + 8*WT]=v[7];
    }
    __syncthreads();
    const int co = tid >> 1, w0l = (tid & 1) * 8;
    float acc[8];
    #pragma unroll
    for (int i = 0; i < 8; ++i) acc[i] = 0.0f;
    for (int c = 0; c < C_; ++c) {
        #pragma unroll
        for (int t = 0; t < 9; ++t) {
            const float wv = Wg[(co * C_ + c) * 9 + t];
            const float* zp = &Zl[(c * 9 + t) * WT + w0l];
            const float4 za = *(const float4*)zp;
            const float4 zb = *(const float4*)(zp + 4);
            acc[0]=fmaf(za.x,wv,acc[0]); acc[1]=fmaf(za.y,wv,acc[1]);
            acc[2]=fmaf(za.z,wv,acc[2]); acc[3]=fmaf(za.w,wv,acc[3]);
            acc[4]=fmaf(zb.x,wv,acc[4]); acc[5]=fmaf(zb.y,wv,acc[5]);
            acc[6]=fmaf(zb.z,wv,acc[6]); acc[7]=fmaf(zb.w,wv,acc[7]);
        }
    }
    const float bv = bias[co];
    float* op = out + ((b * CO_ + co) * H_ + h) * W_ + w0 + w0l;
    *(float4*)(op)     = make_float4(acc[0]+bv, acc[1]+bv, acc[2]+bv, acc[3]+bv);
    *(float4*)(op + 4) = make_float4(acc[4]+bv, acc[5]+bv, acc[6]+bv, acc[7]+bv);
}

extern "C" void kernel_launch(void* const* d_in, const int* in_sizes, int n_in,
                              void* d_out, int out_size, void* d_ws, size_t ws_size,
                              hipStream_t stream) {
    const float* x    = (const float*)d_in[0];
    const float* Coef = (const float*)d_in[1];
    const float* Wg   = (const float*)d_in[2];
    const float* bias = (const float*)d_in[3];
    float* out = (float*)d_out;

    const size_t need = (size_t)CO_ * K_ * sizeof(ushort);   // 147456 B
    if (ws_size >= need) {
        ushort* Wb = (ushort*)d_ws;
        conv_W_bf16<<<(CO_ * K_ + 255) / 256, 256, 0, stream>>>(Wg, Wb);
        sconv_mfma<<<B_ * (H_ / 16) * (W_ / 16), 512, 0, stream>>>(x, Coef, Wb, bias, out);
    } else {
        sconv_fp32<<<B_ * H_ * 8, 256, 0, stream>>>(x, Coef, Wg, bias, out);
    }
}